// Round 21
// baseline (100.628 us; speedup 1.0000x reference)
//
#include <hip/hip_runtime.h>
#include <hip/hip_bf16.h>

typedef __attribute__((ext_vector_type(8))) short bf16x8;
typedef __attribute__((ext_vector_type(4))) float f32x4;
typedef __attribute__((ext_vector_type(4))) unsigned u32x4;

#define NEG 0.2f
#define CST 104         // bf16 elems per LDS row (208 B stride)
#define HSTRIDE 11648   // 112*104 bf16 elems per head in d_ws
#define POFF 24192      // P region byte offset in LDS

__device__ __forceinline__ float lrelu(float x) { return x >= 0.0f ? x : NEG * x; }

// packed pair via v_cvt_pk_bf16_f32 (RNE)
__device__ __forceinline__ unsigned pk2(float a, float b) {
    __hip_bfloat162 h = __float22bfloat162_rn(float2{a, b});
    unsigned r;
    __builtin_memcpy(&r, &h, sizeof(r));
    return r;
}
__device__ __forceinline__ float bflo(unsigned u) {
    unsigned v = u << 16; float f; __builtin_memcpy(&f, &v, 4); return f;
}
__device__ __forceinline__ float bfhi(unsigned u) {
    unsigned v = u & 0xffff0000u; float f; __builtin_memcpy(&f, &v, 4); return f;
}

// ---- prep (fast): Wp[h] = [112][104] bf16, exact LDS image ----
extern "C" __global__ void prep_w(const float* __restrict__ W,
                                  const float* __restrict__ att_src,
                                  const float* __restrict__ att_dst,
                                  unsigned short* __restrict__ Wp)
{
    __shared__ float red[2][4][128];
    __shared__ float sWS[128], sWD[128];
    const int h = blockIdx.x, tid = threadIdx.x;
    const int f = tid & 127, og = tid >> 7;
    const float* __restrict__ Wh = W + h * 10000;
    float ws = 0.0f, wd = 0.0f;
    if (f < 100) {
        for (int o = og * 25; o < og * 25 + 25; ++o) {
            float wv = Wh[o * 100 + f];
            ws = fmaf(att_src[h * 100 + o], wv, ws);
            wd = fmaf(att_dst[h * 100 + o], wv, wd);
        }
    }
    red[0][og][f] = ws;
    red[1][og][f] = wd;
    __syncthreads();
    if (tid < 256) {
        const int which = tid >> 7, ff = tid & 127;
        float s = (red[which][0][ff] + red[which][1][ff]) +
                  (red[which][2][ff] + red[which][3][ff]);
        (which ? sWD : sWS)[ff] = s;
    }
    __syncthreads();
    unsigned short* __restrict__ D = Wp + h * HSTRIDE;
    for (int q = tid; q < 2912; q += 512) {
        const int o = q / 26, f0 = (q - o * 26) * 4;
        uint2 pp = {0u, 0u};
        if (f0 < 100) {
            if (o < 100) {
                float4 wv = *(const float4*)(Wh + o * 100 + f0);
                pp.x = pk2(wv.x, wv.y);
                pp.y = pk2(wv.z, wv.w);
            } else if (o == 100) {
                pp.x = pk2(sWS[f0], sWS[f0 + 1]);
                pp.y = pk2(sWS[f0 + 2], sWS[f0 + 3]);
            } else if (o == 101) {
                pp.x = pk2(sWD[f0], sWD[f0 + 1]);
                pp.y = pk2(sWD[f0 + 2], sWD[f0 + 3]);
            }
        }
        *(uint2*)(D + o * CST + f0) = pp;
    }
}

// One block per t. 256 threads = 4 waves; wave w owns row-tiles {w, w+4}
// (wave 3 duplicates its tile, writes suppressed — r6's proven-clean register
// shape). Each B-fragment (P in GEMM-1, HT in PV) is read ONCE per wave and
// feeds BOTH rows' MFMAs: total LDS b128 reads drop 1568 -> 896 per block
// (the r20 profile showed LDS-read BW = ~2/3 of runtime).
// LDS 47744 B -> 3 blocks/CU. __launch_bounds__(256,3) (r5/r6-proven).
// LDS: HT [112][104] bf16 @0; sas[112] @23296, sad[112] @23744 (f32,
//      sas[100..111] = -1e30); P [112][104] bf16 @24192 (+256 B pad).
// Async Wfill via global_load_lds for head h+1 issued after barrier (c).
// 2 barriers/head. Logits free from GEMM-1 tile 6. Low-pressure PVprep.
extern "C" __global__ void __launch_bounds__(256, 3)
gat20(const float* __restrict__ A, const unsigned short* __restrict__ Wp,
      const float* __restrict__ bias, float* __restrict__ out)
{
    extern __shared__ char smem[];
    unsigned short* HT = (unsigned short*)smem;
    float* sas  = (float*)(smem + 23296);
    float* sad  = (float*)(smem + 23744);
    unsigned short* P  = (unsigned short*)(smem + POFF);
    float* sOut = (float*)smem;

    const int t    = blockIdx.x;
    const int tid  = threadIdx.x;      // 0..255
    const int w    = tid >> 6;         // 0..3
    const int l    = tid & 63;
    const int lr   = l & 15;
    const int lk   = l >> 4;
    const bool HAS2 = (w < 3);
    const int tr1  = HAS2 ? (w + 4) : w;       // wave 3 duplicates its tile
    const int j00  = w * 16 + 4 * lk;          // <= 60, always valid
    const int j01  = tr1 * 16 + 4 * lk;        // up to 108
    const bool JW1 = HAS2 && (j01 < 104);
    const float* __restrict__ At = A + (size_t)t * 10000u;
    const f32x4 z4 = {0, 0, 0, 0};

    // ---- init stats: sas[100..111] = -1e30, rest 0 ----
    if (tid < 224) {
        float v = (tid >= 100 && tid < 112) ? -1e30f : 0.0f;
        ((float*)(smem + 23296))[tid] = v;
    }
    if (tid >= 224 && tid < 240) ((unsigned*)smem)[tid - 224] = 0;  // HT head guard

    // ---- async Wfill(0) into P (6 chunk-groups of 64 per wave) ----
    {
        const char* Wg = (const char*)Wp;
#pragma unroll
        for (int k = 0; k < 6; ++k) {
            const int c0 = k * 256 + w * 64;
            if (c0 < 1456)
                __builtin_amdgcn_global_load_lds(
                    (const __attribute__((address_space(1))) unsigned*)(Wg + c0 * 16 + l * 16),
                    (__attribute__((address_space(3))) unsigned*)(smem + POFF + c0 * 16),
                    16, 0, 0);
        }
    }

    // ---- xf: direct global loads of X fragments for both row-tiles ----
    const int col0 = w * 16 + lr;        // <= 63, always < 100
    const int col1 = tr1 * 16 + lr;      // up to 111
    const bool c1OK = col1 < 100;
    bf16x8 xf[2][4];
#pragma unroll
    for (int ks = 0; ks < 4; ++ks) {
        const bool kill = (ks == 3) && (lk != 0);
        const int koff = ks * 32 + lk * 8;
        u32x4 uv0 = {0u, 0u, 0u, 0u}, uv1 = {0u, 0u, 0u, 0u};
        if (!kill) {
#pragma unroll
            for (int jp = 0; jp < 4; ++jp) {
                const int f0 = koff + jp * 2;
                const bool g0 = (f0 < 100), g1 = (f0 + 1 < 100);
                float a0 = g0 ? At[f0 * 100 + col0] : 0.0f;
                float a1 = g1 ? At[(f0 + 1) * 100 + col0] : 0.0f;
                uv0[jp] = pk2(a0, a1);
                float b0 = (g0 && c1OK) ? At[f0 * 100 + col1] : 0.0f;
                float b1 = (g1 && c1OK) ? At[(f0 + 1) * 100 + col1] : 0.0f;
                uv1[jp] = pk2(b0, b1);
            }
        }
        xf[0][ks] = __builtin_bit_cast(bf16x8, uv0);
        xf[1][ks] = __builtin_bit_cast(bf16x8, uv1);
    }
    __syncthreads();   // (b0): drains Wfill(0); stats visible

    f32x4 acc[2][7];
#pragma unroll
    for (int r = 0; r < 2; ++r)
#pragma unroll
        for (int c = 0; c < 7; ++c) acc[r][c] = z4;

    for (int h = 0; h < 4; ++h) {
        // ---- GEMM-1, two N-halves; B read once, feeds both rows ----
#pragma unroll
        for (int half = 0; half < 2; ++half) {
            const int ntn = half ? 3 : 4;
            f32x4 c0[4], c1[4];
#pragma unroll
            for (int cc = 0; cc < 4; ++cc) { c0[cc] = z4; c1[cc] = z4; }
            __builtin_amdgcn_s_setprio(1);
#pragma unroll
            for (int ks = 0; ks < 4; ++ks) {
                const int koff = ks * 32 + lk * 8;   // A-side zero kills k-pad
                bf16x8 b[4];
#pragma unroll
                for (int bb = 0; bb < 4; ++bb)
                    if (bb < ntn)
                        b[bb] = *(const bf16x8*)(P + ((half * 4 + bb) * 16 + lr) * CST + koff);
#pragma unroll
                for (int bb = 0; bb < 4; ++bb)
                    if (bb < ntn) {
                        c0[bb] = __builtin_amdgcn_mfma_f32_16x16x32_bf16(xf[0][ks], b[bb], c0[bb], 0, 0, 0);
                        c1[bb] = __builtin_amdgcn_mfma_f32_16x16x32_bf16(xf[1][ks], b[bb], c1[bb], 0, 0, 0);
                    }
            }
            __builtin_amdgcn_s_setprio(0);
#pragma unroll
            for (int bb = 0; bb < 4; ++bb)
                if (bb < ntn) {
                    const int o = (half * 4 + bb) * 16 + lr;
                    {   // row0: j00 <= 60, always in range
                        uint2 pp;
                        pp.x = pk2(c0[bb].x, c0[bb].y);
                        pp.y = pk2(c0[bb].z, c0[bb].w);
                        *(uint2*)(HT + o * CST + j00) = pp;
                    }
                    if (JW1) {
                        uint2 pp;
                        pp.x = pk2(c1[bb].x, c1[bb].y);
                        pp.y = pk2(c1[bb].z, c1[bb].w);
                        *(uint2*)(HT + o * CST + j01) = pp;
                    }
                }
            if (half == 1) {   // tile 6 C-cols 100/101 = a_s, a_d
                if (lr == 4) {
                    *(f32x4*)(sas + j00) = c0[2];
                    if (HAS2 && j01 < 100) *(f32x4*)(sas + j01) = c1[2];
                }
                if (lr == 5) {
                    *(f32x4*)(sad + j00) = c0[2];
                    if (JW1) *(f32x4*)(sad + j01) = c1[2];
                }
            }
        }
        __syncthreads();   // (c) HT + sas/sad ready; P idle from here

        // ---- async Wfill(h+1): hides under PVprep + PV ----
        if (h < 3) {
            const char* Wg = (const char*)(Wp + (h + 1) * HSTRIDE);
#pragma unroll
            for (int k = 0; k < 6; ++k) {
                const int c0i = k * 256 + w * 64;
                if (c0i < 1456)
                    __builtin_amdgcn_global_load_lds(
                        (const __attribute__((address_space(1))) unsigned*)(Wg + c0i * 16 + l * 16),
                        (__attribute__((address_space(3))) unsigned*)(smem + POFF + c0i * 16),
                        16, 0, 0);
            }
        }

        // ---- PVprep: both rows, shared sas reads; unnorm bf16 + rescale ----
        const float adi0 = sad[col0];
        const float adi1 = sad[col1];
        float sE0 = 0.0f, sE1 = 0.0f;
        bf16x8 af0[4], af1[4];
#pragma unroll
        for (int ks = 0; ks < 4; ++ks) {
            const bool dead = (ks == 3) && (lk != 0);
            const int jb = dead ? 64 : ks * 32 + lk * 8;
            const f32x4 s0 = *(const f32x4*)(sas + jb);
            const f32x4 s1 = *(const f32x4*)(sas + jb + 4);
            {
                float e0 = dead ? 0.0f : __expf(lrelu(adi0 + s0.x));
                float e1 = dead ? 0.0f : __expf(lrelu(adi0 + s0.y));
                float e2 = dead ? 0.0f : __expf(lrelu(adi0 + s0.z));
                float e3 = dead ? 0.0f : __expf(lrelu(adi0 + s0.w));
                float e4 = dead ? 0.0f : __expf(lrelu(adi0 + s1.x));
                float e5 = dead ? 0.0f : __expf(lrelu(adi0 + s1.y));
                float e6 = dead ? 0.0f : __expf(lrelu(adi0 + s1.z));
                float e7 = dead ? 0.0f : __expf(lrelu(adi0 + s1.w));
                sE0 += ((e0 + e1) + (e2 + e3)) + ((e4 + e5) + (e6 + e7));
                u32x4 uv;
                uv.x = pk2(e0, e1); uv.y = pk2(e2, e3);
                uv.z = pk2(e4, e5); uv.w = pk2(e6, e7);
                af0[ks] = __builtin_bit_cast(bf16x8, uv);
            }
            {
                float e0 = dead ? 0.0f : __expf(lrelu(adi1 + s0.x));
                float e1 = dead ? 0.0f : __expf(lrelu(adi1 + s0.y));
                float e2 = dead ? 0.0f : __expf(lrelu(adi1 + s0.z));
                float e3 = dead ? 0.0f : __expf(lrelu(adi1 + s0.w));
                float e4 = dead ? 0.0f : __expf(lrelu(adi1 + s1.x));
                float e5 = dead ? 0.0f : __expf(lrelu(adi1 + s1.y));
                float e6 = dead ? 0.0f : __expf(lrelu(adi1 + s1.z));
                float e7 = dead ? 0.0f : __expf(lrelu(adi1 + s1.w));
                sE1 += ((e0 + e1) + (e2 + e3)) + ((e4 + e5) + (e6 + e7));
                u32x4 uv;
                uv.x = pk2(e0, e1); uv.y = pk2(e2, e3);
                uv.z = pk2(e4, e5); uv.w = pk2(e6, e7);
                af1[ks] = __builtin_bit_cast(bf16x8, uv);
            }
        }
        sE0 += __shfl_xor(sE0, 16);
        sE0 += __shfl_xor(sE0, 32);
        sE1 += __shfl_xor(sE1, 16);
        sE1 += __shfl_xor(sE1, 32);
        const float invE0 = sE0 > 0.0f ? __builtin_amdgcn_rcpf(sE0) : 0.0f;
        const float invE1 = sE1 > 0.0f ? __builtin_amdgcn_rcpf(sE1) : 0.0f;
#pragma unroll
        for (int ks = 0; ks < 4; ++ks) {
            u32x4 u0 = __builtin_bit_cast(u32x4, af0[ks]);
            u0.x = pk2(bflo(u0.x) * invE0, bfhi(u0.x) * invE0);
            u0.y = pk2(bflo(u0.y) * invE0, bfhi(u0.y) * invE0);
            u0.z = pk2(bflo(u0.z) * invE0, bfhi(u0.z) * invE0);
            u0.w = pk2(bflo(u0.w) * invE0, bfhi(u0.w) * invE0);
            af0[ks] = __builtin_bit_cast(bf16x8, u0);
            u32x4 u1 = __builtin_bit_cast(u32x4, af1[ks]);
            u1.x = pk2(bflo(u1.x) * invE1, bfhi(u1.x) * invE1);
            u1.y = pk2(bflo(u1.y) * invE1, bfhi(u1.y) * invE1);
            u1.z = pk2(bflo(u1.z) * invE1, bfhi(u1.z) * invE1);
            u1.w = pk2(bflo(u1.w) * invE1, bfhi(u1.w) * invE1);
            af1[ks] = __builtin_bit_cast(bf16x8, u1);
        }

        // ---- PV: B read once, feeds both rows; direct acc ----
        __builtin_amdgcn_s_setprio(1);
#pragma unroll
        for (int half = 0; half < 2; ++half) {
            const int ntn = half ? 3 : 4;
#pragma unroll
            for (int ks = 0; ks < 4; ++ks) {
                const int koff = ks * 32 + lk * 8;
                bf16x8 b[4];
#pragma unroll
                for (int bb = 0; bb < 4; ++bb)
                    if (bb < ntn)
                        b[bb] = *(const bf16x8*)(HT + ((half * 4 + bb) * 16 + lr) * CST + koff);
#pragma unroll
                for (int bb = 0; bb < 4; ++bb)
                    if (bb < ntn) {
                        acc[0][half * 4 + bb] = __builtin_amdgcn_mfma_f32_16x16x32_bf16(
                            af0[ks], b[bb], acc[0][half * 4 + bb], 0, 0, 0);
                        acc[1][half * 4 + bb] = __builtin_amdgcn_mfma_f32_16x16x32_bf16(
                            af1[ks], b[bb], acc[1][half * 4 + bb], 0, 0, 0);
                    }
            }
        }
        __builtin_amdgcn_s_setprio(0);
        __syncthreads();   // (d): drains Wfill(h+1); HT reusable
    }

    // ---- epilogue: sOut[o][i] = lrelu(acc*0.25 + bias[o]) + (i==o) ----
    {
        const int i0 = j00;
#pragma unroll
        for (int tn = 0; tn < 7; ++tn) {
            const int o = tn * 16 + lr;
            const float b = (o < 100) ? bias[o] : 0.0f;
            f32x4 v;
            v.x = lrelu(acc[0][tn].x * 0.25f + b) + ((i0 + 0) == o ? 1.0f : 0.0f);
            v.y = lrelu(acc[0][tn].y * 0.25f + b) + ((i0 + 1) == o ? 1.0f : 0.0f);
            v.z = lrelu(acc[0][tn].z * 0.25f + b) + ((i0 + 2) == o ? 1.0f : 0.0f);
            v.w = lrelu(acc[0][tn].w * 0.25f + b) + ((i0 + 3) == o ? 1.0f : 0.0f);
            *(f32x4*)(sOut + o * 104 + i0) = v;
        }
    }
    if (JW1) {
        const int i0 = j01;
#pragma unroll
        for (int tn = 0; tn < 7; ++tn) {
            const int o = tn * 16 + lr;
            const float b = (o < 100) ? bias[o] : 0.0f;
            f32x4 v;
            v.x = lrelu(acc[1][tn].x * 0.25f + b) + ((i0 + 0) == o ? 1.0f : 0.0f);
            v.y = lrelu(acc[1][tn].y * 0.25f + b) + ((i0 + 1) == o ? 1.0f : 0.0f);
            v.z = lrelu(acc[1][tn].z * 0.25f + b) + ((i0 + 2) == o ? 1.0f : 0.0f);
            v.w = lrelu(acc[1][tn].w * 0.25f + b) + ((i0 + 3) == o ? 1.0f : 0.0f);
            *(f32x4*)(sOut + o * 104 + i0) = v;
        }
    }
    __syncthreads();

    // ---- coalesced store out[t][o][i] ----
    float* __restrict__ outT = out + (size_t)t * 10000u;
    for (int q = tid; q < 2500; q += 256) {
        int o = q / 25, i0 = (q - o * 25) * 4;
        *(float4*)(outT + o * 100 + i0) = *(const float4*)(sOut + o * 104 + i0);
    }
}

extern "C" void kernel_launch(void* const* d_in, const int* in_sizes, int n_in,
                              void* d_out, int out_size, void* d_ws, size_t ws_size,
                              hipStream_t stream) {
    const float* A      = (const float*)d_in[0];
    const float* W      = (const float*)d_in[1];
    const float* attsrc = (const float*)d_in[2];
    const float* attdst = (const float*)d_in[3];
    const float* bias   = (const float*)d_in[4];
    float* outp = (float*)d_out;
    unsigned short* Wp = (unsigned short*)d_ws;   // 4*11648*2 = 93184 B (+tail pad)

    const int T = in_sizes[0] / 10000;   // 1024

    prep_w<<<4, 512, 0, stream>>>(W, attsrc, attdst, Wp);

    const int smem_bytes = 47744;
    gat20<<<T, 256, smem_bytes, stream>>>(A, Wp, bias, outp);
}

// Round 22
// 63.968 us; speedup vs baseline: 1.5731x; 1.5731x over previous
//
#include <hip/hip_runtime.h>
#include <hip/hip_bf16.h>

typedef __attribute__((ext_vector_type(8))) short bf16x8;
typedef __attribute__((ext_vector_type(4))) float f32x4;
typedef __attribute__((ext_vector_type(4))) unsigned u32x4;

#define NEG 0.2f
#define CST 104         // bf16 elems per LDS row (208 B stride)
#define HSTRIDE 11648   // 112*104 bf16 elems per head in d_ws
#define POFF 24192      // P region byte offset in LDS

__device__ __forceinline__ float lrelu(float x) { return x >= 0.0f ? x : NEG * x; }

// packed pair via v_cvt_pk_bf16_f32 (RNE)
__device__ __forceinline__ unsigned pk2(float a, float b) {
    __hip_bfloat162 h = __float22bfloat162_rn(float2{a, b});
    unsigned r;
    __builtin_memcpy(&r, &h, sizeof(r));
    return r;
}
__device__ __forceinline__ float bflo(unsigned u) {
    unsigned v = u << 16; float f; __builtin_memcpy(&f, &v, 4); return f;
}
__device__ __forceinline__ float bfhi(unsigned u) {
    unsigned v = u & 0xffff0000u; float f; __builtin_memcpy(&f, &v, 4); return f;
}

// ---- prep (fast): Wp[h] = [112][104] bf16, exact LDS image ----
extern "C" __global__ void prep_w(const float* __restrict__ W,
                                  const float* __restrict__ att_src,
                                  const float* __restrict__ att_dst,
                                  unsigned short* __restrict__ Wp)
{
    __shared__ float red[2][4][128];
    __shared__ float sWS[128], sWD[128];
    const int h = blockIdx.x, tid = threadIdx.x;
    const int f = tid & 127, og = tid >> 7;
    const float* __restrict__ Wh = W + h * 10000;
    float ws = 0.0f, wd = 0.0f;
    if (f < 100) {
        for (int o = og * 25; o < og * 25 + 25; ++o) {
            float wv = Wh[o * 100 + f];
            ws = fmaf(att_src[h * 100 + o], wv, ws);
            wd = fmaf(att_dst[h * 100 + o], wv, wd);
        }
    }
    red[0][og][f] = ws;
    red[1][og][f] = wd;
    __syncthreads();
    if (tid < 256) {
        const int which = tid >> 7, ff = tid & 127;
        float s = (red[which][0][ff] + red[which][1][ff]) +
                  (red[which][2][ff] + red[which][3][ff]);
        (which ? sWD : sWS)[ff] = s;
    }
    __syncthreads();
    unsigned short* __restrict__ D = Wp + h * HSTRIDE;
    for (int q = tid; q < 2912; q += 512) {
        const int o = q / 26, f0 = (q - o * 26) * 4;
        uint2 pp = {0u, 0u};
        if (f0 < 100) {
            if (o < 100) {
                float4 wv = *(const float4*)(Wh + o * 100 + f0);
                pp.x = pk2(wv.x, wv.y);
                pp.y = pk2(wv.z, wv.w);
            } else if (o == 100) {
                pp.x = pk2(sWS[f0], sWS[f0 + 1]);
                pp.y = pk2(sWS[f0 + 2], sWS[f0 + 3]);
            } else if (o == 101) {
                pp.x = pk2(sWD[f0], sWD[f0 + 1]);
                pp.y = pk2(sWD[f0 + 2], sWD[f0 + 3]);
            }
        }
        *(uint2*)(D + o * CST + f0) = pp;
    }
}

// One block per t. 512 threads = 8 waves; waves 0..6 compute one 16-row tile
// each; wave 7 staging+barriers only. LDS 47744 B. (512,4) envelope (the only
// clean one — r10..r21 evidence; every expansion attempt spilled).
// LDS: HT [112][104] bf16 @0; sas[112] @23296, sad[112] @23744 (f32,
//      sas[100..111] = -1e30); P [112][104] bf16 @24192 (+256 B pad).
// Async Wfill (global_load_lds, 16B) for head h+1 issued after barrier (c);
// loop-end barrier's vmcnt(0) drain lands it. 2 barriers/head. Logits free
// from GEMM-1 tile 6. Low-pressure PVprep (per-ks transient exps -> bf16,
// bf16-domain rescale). Epilogue stores DIRECTLY from acc registers to
// global (16B f32x4, 64B/lk-group) — no sOut LDS round-trip, no extra
// barriers (r22 change).
extern "C" __global__ void __launch_bounds__(512, 4)
gat21(const float* __restrict__ A, const unsigned short* __restrict__ Wp,
      const float* __restrict__ bias, float* __restrict__ out)
{
    extern __shared__ char smem[];
    unsigned short* HT = (unsigned short*)smem;
    float* sas  = (float*)(smem + 23296);
    float* sad  = (float*)(smem + 23744);
    unsigned short* P  = (unsigned short*)(smem + POFF);

    const int t    = blockIdx.x;
    const int tid  = threadIdx.x;      // 0..511
    const int w    = tid >> 6;         // 0..7
    const int l    = tid & 63;
    const int lr   = l & 15;
    const int lk   = l >> 4;
    const bool HASW = (w < 7);
    const int row  = HASW ? w : 6;
    const int j0   = row * 16 + 4 * lk;        // 0..108
    const bool JW  = HASW && (j0 < 104);
    const float* __restrict__ At = A + (size_t)t * 10000u;
    const f32x4 z4 = {0, 0, 0, 0};

    // ---- init stats: sas[0..111] (pads -1e30), sad[0..111] = 0 ----
    if (tid < 224) {
        float v = (tid >= 100 && tid < 112) ? -1e30f : 0.0f;
        ((float*)(smem + 23296))[tid] = v;
    }

    // ---- async Wfill(0): fire-and-forget into P (drained at 1st barrier) ----
    {
        const char* Wg = (const char*)Wp;   // head 0
#pragma unroll
        for (int k = 0; k < 3; ++k) {
            const int c0 = k * 512 + w * 64;
            if (c0 < 1456)
                __builtin_amdgcn_global_load_lds(
                    (const __attribute__((address_space(1))) unsigned*)(Wg + c0 * 16 + l * 16),
                    (__attribute__((address_space(3))) unsigned*)(smem + POFF + c0 * 16),
                    16, 0, 0);
        }
    }

    // ---- xf: direct global loads of X = A_t^T fragments (waves 0..6) ----
    const int col = row * 16 + lr;
    const bool cOK = HASW && (col < 100);
    bf16x8 xf[4];
#pragma unroll
    for (int ks = 0; ks < 4; ++ks) {
        const bool kill = (ks == 3) && (lk != 0);
        const int koff = ks * 32 + lk * 8;
        u32x4 uv = {0u, 0u, 0u, 0u};
        if (cOK && !kill) {
#pragma unroll
            for (int jp = 0; jp < 4; ++jp) {
                const int f0 = koff + jp * 2;
                float a0 = (f0     < 100) ? At[f0 * 100 + col]       : 0.0f;
                float a1 = (f0 + 1 < 100) ? At[(f0 + 1) * 100 + col] : 0.0f;
                uv[jp] = pk2(a0, a1);
            }
        }
        xf[ks] = __builtin_bit_cast(bf16x8, uv);
    }
    __syncthreads();   // (b0): drains Wfill(0) vmcnt; stats visible

    f32x4 acc[7];
#pragma unroll
    for (int c = 0; c < 7; ++c) acc[c] = z4;

    for (int h = 0; h < 4; ++h) {
        if (HASW) {
            // ---- GEMM-1, two N-halves; logits free from tile 6 ----
#pragma unroll
            for (int half = 0; half < 2; ++half) {
                const int ntn = half ? 3 : 4;
                f32x4 c[4];
#pragma unroll
                for (int cc = 0; cc < 4; ++cc) c[cc] = z4;
                __builtin_amdgcn_s_setprio(1);
#pragma unroll
                for (int ks = 0; ks < 4; ++ks) {
                    const int koff = ks * 32 + lk * 8;   // A-side zero kills k-pad
                    bf16x8 b[4];
#pragma unroll
                    for (int bb = 0; bb < 4; ++bb)
                        if (bb < ntn)
                            b[bb] = *(const bf16x8*)(P + ((half * 4 + bb) * 16 + lr) * CST + koff);
#pragma unroll
                    for (int bb = 0; bb < 4; ++bb)
                        if (bb < ntn)
                            c[bb] = __builtin_amdgcn_mfma_f32_16x16x32_bf16(xf[ks], b[bb], c[bb], 0, 0, 0);
                }
                __builtin_amdgcn_s_setprio(0);
#pragma unroll
                for (int bb = 0; bb < 4; ++bb)
                    if (bb < ntn) {
                        const int o = (half * 4 + bb) * 16 + lr;
                        if (JW) {
                            uint2 pp;
                            pp.x = pk2(c[bb].x, c[bb].y);
                            pp.y = pk2(c[bb].z, c[bb].w);
                            *(uint2*)(HT + o * CST + j0) = pp;
                        }
                    }
                if (half == 1) {   // tile 6 C-cols 100/101 = a_s, a_d
                    if (lr == 4 && j0 < 100) *(f32x4*)(sas + j0) = c[2];
                    if (lr == 5 && JW)       *(f32x4*)(sad + j0) = c[2];
                }
            }
        }
        __syncthreads();   // (c) HT + sas/sad ready; P idle from here

        // ---- async Wfill(h+1) into P: latency hides under PVprep+PV ----
        if (h < 3) {
            const char* Wg = (const char*)(Wp + (h + 1) * HSTRIDE);
#pragma unroll
            for (int k = 0; k < 3; ++k) {
                const int c0 = k * 512 + w * 64;
                if (c0 < 1456)
                    __builtin_amdgcn_global_load_lds(
                        (const __attribute__((address_space(1))) unsigned*)(Wg + c0 * 16 + l * 16),
                        (__attribute__((address_space(3))) unsigned*)(smem + POFF + c0 * 16),
                        16, 0, 0);
            }
        }

        if (HASW) {
            // ---- PVprep: per-ks transient exps -> unnorm bf16 af; f32 sum ----
            const float adi = sad[row * 16 + lr];
            float sE = 0.0f;
            bf16x8 af[4];
#pragma unroll
            for (int ks = 0; ks < 4; ++ks) {
                const bool dead = (ks == 3) && (lk != 0);
                const int jb = dead ? 64 : ks * 32 + lk * 8;
                const f32x4 s0 = *(const f32x4*)(sas + jb);
                const f32x4 s1 = *(const f32x4*)(sas + jb + 4);
                float e0 = dead ? 0.0f : __expf(lrelu(adi + s0.x));
                float e1 = dead ? 0.0f : __expf(lrelu(adi + s0.y));
                float e2 = dead ? 0.0f : __expf(lrelu(adi + s0.z));
                float e3 = dead ? 0.0f : __expf(lrelu(adi + s0.w));
                float e4 = dead ? 0.0f : __expf(lrelu(adi + s1.x));
                float e5 = dead ? 0.0f : __expf(lrelu(adi + s1.y));
                float e6 = dead ? 0.0f : __expf(lrelu(adi + s1.z));
                float e7 = dead ? 0.0f : __expf(lrelu(adi + s1.w));
                sE += ((e0 + e1) + (e2 + e3)) + ((e4 + e5) + (e6 + e7));
                u32x4 uv;
                uv.x = pk2(e0, e1); uv.y = pk2(e2, e3);
                uv.z = pk2(e4, e5); uv.w = pk2(e6, e7);
                af[ks] = __builtin_bit_cast(bf16x8, uv);
            }
            sE += __shfl_xor(sE, 16);
            sE += __shfl_xor(sE, 32);
            const float invE = sE > 0.0f ? __builtin_amdgcn_rcpf(sE) : 0.0f;
#pragma unroll
            for (int ks = 0; ks < 4; ++ks) {   // bf16-domain rescale
                u32x4 uv = __builtin_bit_cast(u32x4, af[ks]);
                uv.x = pk2(bflo(uv.x) * invE, bfhi(uv.x) * invE);
                uv.y = pk2(bflo(uv.y) * invE, bfhi(uv.y) * invE);
                uv.z = pk2(bflo(uv.z) * invE, bfhi(uv.z) * invE);
                uv.w = pk2(bflo(uv.w) * invE, bfhi(uv.w) * invE);
                af[ks] = __builtin_bit_cast(bf16x8, uv);
            }

            // ---- PV: acc += alpha * H (direct C accumulation) ----
            __builtin_amdgcn_s_setprio(1);
#pragma unroll
            for (int half = 0; half < 2; ++half) {
                const int ntn = half ? 3 : 4;
#pragma unroll
                for (int ks = 0; ks < 4; ++ks) {
                    const int koff = ks * 32 + lk * 8;
                    bf16x8 b[4];
#pragma unroll
                    for (int bb = 0; bb < 4; ++bb)
                        if (bb < ntn)
                            b[bb] = *(const bf16x8*)(HT + ((half * 4 + bb) * 16 + lr) * CST + koff);
#pragma unroll
                    for (int bb = 0; bb < 4; ++bb)
                        if (bb < ntn)
                            acc[half * 4 + bb] = __builtin_amdgcn_mfma_f32_16x16x32_bf16(
                                af[ks], b[bb], acc[half * 4 + bb], 0, 0, 0);
                }
            }
            __builtin_amdgcn_s_setprio(0);
        }
        __syncthreads();   // (d): drains Wfill(h+1) -> P ready; HT reusable
    }

    // ---- epilogue: DIRECT register->global stores (no LDS round-trip) ----
    // lane holds out rows i0..i0+3 (i0 = j0) for cols o = tn*16+lr.
    // 16B f32x4 at outT + o*100 + j0: (o*100 + j0) % 4 == 0 -> 16B aligned.
    if (HASW && j0 < 100) {   // j0 == 100 was sOut-pad, never emitted
        float* __restrict__ outT = out + (size_t)t * 10000u;
#pragma unroll
        for (int tn = 0; tn < 7; ++tn) {
            const int o = tn * 16 + lr;
            if (o < 100) {
                const float b = bias[o];
                f32x4 v;
                v.x = lrelu(acc[tn].x * 0.25f + b) + ((j0 + 0) == o ? 1.0f : 0.0f);
                v.y = lrelu(acc[tn].y * 0.25f + b) + ((j0 + 1) == o ? 1.0f : 0.0f);
                v.z = lrelu(acc[tn].z * 0.25f + b) + ((j0 + 2) == o ? 1.0f : 0.0f);
                v.w = lrelu(acc[tn].w * 0.25f + b) + ((j0 + 3) == o ? 1.0f : 0.0f);
                *(f32x4*)(outT + o * 100 + j0) = v;
            }
        }
    }
}

extern "C" void kernel_launch(void* const* d_in, const int* in_sizes, int n_in,
                              void* d_out, int out_size, void* d_ws, size_t ws_size,
                              hipStream_t stream) {
    const float* A      = (const float*)d_in[0];
    const float* W      = (const float*)d_in[1];
    const float* attsrc = (const float*)d_in[2];
    const float* attdst = (const float*)d_in[3];
    const float* bias   = (const float*)d_in[4];
    float* outp = (float*)d_out;
    unsigned short* Wp = (unsigned short*)d_ws;   // 4*11648*2 = 93184 B

    const int T = in_sizes[0] / 10000;   // 1024

    prep_w<<<4, 512, 0, stream>>>(W, attsrc, attdst, Wp);

    const int smem_bytes = 47744;
    gat21<<<T, 512, smem_bytes, stream>>>(A, Wp, bias, outp);
}